// Round 3
// baseline (25425.635 us; speedup 1.0000x reference)
//
#include <hip/hip_runtime.h>
#include <math.h>
#include <stdint.h>

#define NBATCH 512
#define SLEN   128
#define HDIM   256

// scratch layout in floats (static __device__ — independent of ws_size)
#define OFF_WHE  0            // Wh_enc packed [k][j][4]  262144
#define OFF_WHD  262144       // Wh_dec packed            262144
#define OFF_ME   524288       // M_enc  [k4][j][4]        4096
#define OFF_MD   528384       // M_dec                    4096
#define OFF_VE   532480       // v_enc  [j][4]            1024
#define OFF_VD   533504       // v_dec                    1024
#define OFF_X0   534528       // x0 gates [j][4]          1024
#define OFF_WQG  535552       // WqgT [k][j]              65536
#define OFF_WQP  601088       // WqpT                     65536
#define OFF_WRGP 666624       // (Wr_g,Wr_p) [k][j][2]    131072
#define OFF_RG   797696       // refp_g [B][S][H]         16777216
#define OFF_RP   17574912     // refp_p                   16777216
#define WS_FLOATS 34352128    // ~137.4 MB

__device__ float g_ws[WS_FLOATS];

__device__ __forceinline__ float sigf(float x) { return 1.0f / (1.0f + expf(-x)); }

__device__ __forceinline__ void tf2x32(uint32_t k0, uint32_t k1, uint32_t x0, uint32_t x1,
                                       uint32_t& o0, uint32_t& o1) {
    uint32_t ks2 = k0 ^ k1 ^ 0x1BD11BDAu;
    x0 += k0; x1 += k1;
#define RR(r) { x0 += x1; x1 = (x1 << r) | (x1 >> (32 - r)); x1 ^= x0; }
    RR(13) RR(15) RR(26) RR(6)   x0 += k1;  x1 += ks2 + 1u;
    RR(17) RR(29) RR(16) RR(24)  x0 += ks2; x1 += k0 + 2u;
    RR(13) RR(15) RR(26) RR(6)   x0 += k0;  x1 += k1 + 3u;
    RR(17) RR(29) RR(16) RR(24)  x0 += k1;  x1 += ks2 + 4u;
    RR(13) RR(15) RR(26) RR(6)   x0 += ks2; x1 += k0 + 5u;
#undef RR
    o0 = x0; o1 = x1;
}

// JAX partitionable-threefry random_bits (bit_width=32) for flat element n, key (k0,k1):
// counts = iota(uint64); bits[n] = xor(threefry2x32(key, (n>>32, n&0xffffffff)))
// n < 2^32 here -> input pair (0, n); output = o0 ^ o1.
__device__ __forceinline__ double gumbel_jax(uint32_t k0, uint32_t k1, uint32_t n) {
    uint32_t o0, o1; tf2x32(k0, k1, 0u, n, o0, o1);
    uint32_t bits = o0 ^ o1;
    float f = __uint_as_float((bits >> 9) | 0x3f800000u) - 1.0f;
    f = fmaxf(f, 1.17549435e-38f);  // JAX uniform(minval=tiny): max(tiny, u) in f32
    return -log(-log((double)f));
}

__global__ void pre_k(const float* __restrict__ embed_W, const float* __restrict__ embed_b,
                      const float* __restrict__ Wi_enc, const float* __restrict__ Wh_enc,
                      const float* __restrict__ b_enc,
                      const float* __restrict__ Wi_dec, const float* __restrict__ Wh_dec,
                      const float* __restrict__ b_dec, const float* __restrict__ dec0,
                      const float* __restrict__ Wq_g, const float* __restrict__ Wr_g,
                      const float* __restrict__ Wq_p, const float* __restrict__ Wr_p) {
    float* ws = g_ws;
    int i0 = blockIdx.x * blockDim.x + threadIdx.x;
    int np = gridDim.x * blockDim.x;
    for (int i = i0; i < 262144; i += np) {
        int g = i & 3, j = (i >> 2) & 255, k = i >> 10, r = (g << 8) + j;
        ws[OFF_WHE + i] = Wh_enc[r * 256 + k];
        ws[OFF_WHD + i] = Wh_dec[r * 256 + k];
    }
    for (int i = i0; i < 65536; i += np) {
        int j = i & 255, k = i >> 8;
        ws[OFF_WQG + i] = Wq_g[j * 256 + k];
        ws[OFF_WQP + i] = Wq_p[j * 256 + k];
        ws[OFF_WRGP + 2 * i]     = Wr_g[j * 256 + k];
        ws[OFF_WRGP + 2 * i + 1] = Wr_p[j * 256 + k];
    }
    for (int i = i0; i < 4096; i += np) {
        int g = i & 3, j = (i >> 2) & 255, k4 = i >> 10, r = (g << 8) + j;
        const float* we = embed_W + k4 * 256;
        const float* wa = Wi_enc + r * 256;
        const float* wb = Wi_dec + r * 256;
        double a = 0.0, b = 0.0;
        for (int e = 0; e < 256; ++e) { a += (double)we[e] * wa[e]; b += (double)we[e] * wb[e]; }
        ws[OFF_ME + i] = (float)a; ws[OFF_MD + i] = (float)b;
    }
    for (int i = i0; i < 1024; i += np) {
        int g = i & 3, j = i >> 2, r = (g << 8) + j;
        const float* wa = Wi_enc + r * 256;
        const float* wb = Wi_dec + r * 256;
        double a = 0.0, b = 0.0, x = 0.0;
        for (int e = 0; e < 256; ++e) {
            a += (double)embed_b[e] * wa[e];
            b += (double)embed_b[e] * wb[e];
            x += (double)dec0[e] * wb[e];
        }
        ws[OFF_VE + i] = (float)(a + (double)b_enc[r]);
        ws[OFF_VD + i] = (float)(b + (double)b_dec[r]);
        ws[OFF_X0 + i] = (float)(x + (double)b_dec[r]);
    }
}

__global__ __launch_bounds__(512) void main_k(
    const float* __restrict__ problems,
    const float* __restrict__ bq_g, const float* __restrict__ br_g, const float* __restrict__ V_g,
    const float* __restrict__ bq_p, const float* __restrict__ br_p, const float* __restrict__ V_p,
    float* __restrict__ out) {
    float* ws = g_ws;
    const int blk = blockIdx.x, tid = threadIdx.x;
    const int bb = tid >> 8, j = tid & 255, lane = tid & 63, wave = tid >> 6;
    const int b = (blk << 1) + bb;

    const float4* WhE = (const float4*)(ws + OFF_WHE);
    const float4* WhD = (const float4*)(ws + OFF_WHD);
    const float4* ME  = (const float4*)(ws + OFF_ME);
    const float4* MD  = (const float4*)(ws + OFF_MD);
    const float4* vE  = (const float4*)(ws + OFF_VE);
    const float4* vD  = (const float4*)(ws + OFF_VD);
    const float4* X0  = (const float4*)(ws + OFF_X0);
    const float*  WqgT = ws + OFF_WQG;
    const float*  WqpT = ws + OFF_WQP;
    const float2* Wrgp = (const float2*)(ws + OFF_WRGP);
    float* refg = ws + OFF_RG + (size_t)b * SLEN * HDIM;
    float* refp = ws + OFF_RP + (size_t)b * SLEN * HDIM;

    __shared__ double h_d[2][256];
    __shared__ double q_d[2][256];
    __shared__ double qp_d[2][256];
    __shared__ float u_l[2][128];
    __shared__ float w_l[2][128];
    __shared__ unsigned char vis[2][128];
    __shared__ int lastA[2];

    h_d[bb][j] = 0.0;
    if (j < 128) vis[bb][j] = 0;
    if (j == 0) lastA[bb] = 0;
    double c = 0.0;
    __syncthreads();

    const float* prb = problems + (size_t)b * SLEN * 4;

    // ---------------- encoder (+ refp rows) ----------------
    for (int t = 0; t < SLEN; ++t) {
        float4 p = *(const float4*)(prb + (t << 2));
        float4 v = vE[j];
        float4 m0 = ME[j], m1 = ME[256 + j], m2 = ME[512 + j], m3 = ME[768 + j];
        double a0 = (double)v.x + (double)p.x * m0.x + (double)p.y * m1.x + (double)p.z * m2.x + (double)p.w * m3.x;
        double a1 = (double)v.y + (double)p.x * m0.y + (double)p.y * m1.y + (double)p.z * m2.y + (double)p.w * m3.y;
        double a2 = (double)v.z + (double)p.x * m0.z + (double)p.y * m1.z + (double)p.z * m2.z + (double)p.w * m3.z;
        double a3 = (double)v.w + (double)p.x * m0.w + (double)p.y * m1.w + (double)p.z * m2.w + (double)p.w * m3.w;
#pragma unroll 8
        for (int k = 0; k < 256; ++k) {
            double hk = h_d[bb][k]; float4 wv = WhE[(k << 8) + j];
            a0 += hk * (double)wv.x; a1 += hk * (double)wv.y;
            a2 += hk * (double)wv.z; a3 += hk * (double)wv.w;
        }
        float ig = sigf((float)a0), fg = sigf((float)a1), gg = tanhf((float)a2), og = sigf((float)a3);
        c = (double)fg * c + (double)ig * (double)gg;
        double hn = (double)og * (double)tanhf((float)c);
        __syncthreads();
        h_d[bb][j] = hn;
        __syncthreads();
        double rg = (double)br_g[j], rp_ = (double)br_p[j];
#pragma unroll 8
        for (int k = 0; k < 256; ++k) {
            double hk = h_d[bb][k]; float2 wr = Wrgp[(k << 8) + j];
            rg += hk * (double)wr.x; rp_ += hk * (double)wr.y;
        }
        refg[t * HDIM + j] = (float)rg;
        refp[t * HDIM + j] = (float)rp_;
    }

    // ---------------- decoder ----------------
    for (int t = 0; t < SLEN; ++t) {
        double a0, a1, a2, a3;
        if (t == 0) {
            float4 v = X0[j]; a0 = v.x; a1 = v.y; a2 = v.z; a3 = v.w;
        } else {
            int a = lastA[bb];
            float4 p = *(const float4*)(prb + (a << 2));
            float4 v = vD[j];
            float4 m0 = MD[j], m1 = MD[256 + j], m2 = MD[512 + j], m3 = MD[768 + j];
            a0 = (double)v.x + (double)p.x * m0.x + (double)p.y * m1.x + (double)p.z * m2.x + (double)p.w * m3.x;
            a1 = (double)v.y + (double)p.x * m0.y + (double)p.y * m1.y + (double)p.z * m2.y + (double)p.w * m3.y;
            a2 = (double)v.z + (double)p.x * m0.z + (double)p.y * m1.z + (double)p.z * m2.z + (double)p.w * m3.z;
            a3 = (double)v.w + (double)p.x * m0.w + (double)p.y * m1.w + (double)p.z * m2.w + (double)p.w * m3.w;
        }
#pragma unroll 8
        for (int k = 0; k < 256; ++k) {
            double hk = h_d[bb][k]; float4 wv = WhD[(k << 8) + j];
            a0 += hk * (double)wv.x; a1 += hk * (double)wv.y;
            a2 += hk * (double)wv.z; a3 += hk * (double)wv.w;
        }
        float ig = sigf((float)a0), fg = sigf((float)a1), gg = tanhf((float)a2), og = sigf((float)a3);
        c = (double)fg * c + (double)ig * (double)gg;
        double hn = (double)og * (double)tanhf((float)c);
        __syncthreads();
        h_d[bb][j] = hn;
        __syncthreads();

        // qp_g = h @ Wq_g.T + bq_g
        {
            double qa = (double)bq_g[j];
#pragma unroll 8
            for (int k = 0; k < 256; ++k) qa += h_d[bb][k] * (double)WqgT[(k << 8) + j];
            qp_d[bb][j] = qa;
        }
        __syncthreads();

        // glimpse u
        {
            int myb = wave >> 2;
            const float* rgb = ws + OFF_RG + (size_t)((blk << 1) + myb) * SLEN * HDIM;
            for (int s = (wave & 3); s < SLEN; s += 4) {
                if (vis[myb][s]) continue;
                const float* r0 = rgb + s * HDIM;
                double part = 0.0;
#pragma unroll
                for (int dd = 0; dd < 4; ++dd) {
                    int d = lane + (dd << 6);
                    float arg = (float)(qp_d[myb][d] + (double)r0[d]);
                    part += (double)V_g[d] * (double)(tanhf(arg) * 10.0f);
                }
                for (int off = 32; off; off >>= 1) part += __shfl_xor(part, off, 64);
                if (lane == 0) u_l[myb][s] = (float)part;
            }
        }
        __syncthreads();

        // glimpse softmax -> w_l
        if ((wave & 3) == 0) {
            int myb = wave >> 2;
            int s1 = lane, s2 = lane + 64;
            bool v1 = vis[myb][s1], v2 = vis[myb][s2];
            float m = fmaxf(v1 ? -1e30f : u_l[myb][s1], v2 ? -1e30f : u_l[myb][s2]);
            for (int off = 32; off; off >>= 1) m = fmaxf(m, __shfl_xor(m, off, 64));
            float e1 = v1 ? 0.f : expf(u_l[myb][s1] - m);
            float e2 = v2 ? 0.f : expf(u_l[myb][s2] - m);
            float den = e1 + e2;
            for (int off = 32; off; off >>= 1) den += __shfl_xor(den, off, 64);
            w_l[myb][s1] = e1 / den;
            w_l[myb][s2] = e2 / den;
        }
        __syncthreads();

        // q = sum_s w[s] * refp_g[s,:]
        {
            double q = 0.0;
            for (int s = 0; s < SLEN; ++s)
                if (!vis[bb][s]) q += (double)w_l[bb][s] * (double)refg[s * HDIM + j];
            q_d[bb][j] = q;
        }
        __syncthreads();

        // qp_p = q @ Wq_p.T + bq_p
        {
            double qa = (double)bq_p[j];
#pragma unroll 8
            for (int k = 0; k < 256; ++k) qa += q_d[bb][k] * (double)WqpT[(k << 8) + j];
            qp_d[bb][j] = qa;
        }
        __syncthreads();

        // pointer logits
        {
            int myb = wave >> 2;
            const float* rpb = ws + OFF_RP + (size_t)((blk << 1) + myb) * SLEN * HDIM;
            for (int s = (wave & 3); s < SLEN; s += 4) {
                if (vis[myb][s]) continue;
                const float* r0 = rpb + s * HDIM;
                double part = 0.0;
#pragma unroll
                for (int dd = 0; dd < 4; ++dd) {
                    int d = lane + (dd << 6);
                    float arg = (float)(qp_d[myb][d] + (double)r0[d]);
                    part += (double)V_p[d] * (double)(tanhf(arg) * 10.0f);
                }
                for (int off = 32; off; off >>= 1) part += __shfl_xor(part, off, 64);
                if (lane == 0) u_l[myb][s] = (float)part;
            }
        }
        __syncthreads();

        // sample (gumbel argmax, jax partitionable-threefry, XOR word combine)
        if ((wave & 3) == 0) {
            int myb = wave >> 2;
            int gb = (blk << 1) + myb;
            int s1 = lane, s2 = lane + 64;
            bool v1 = vis[myb][s1], v2 = vis[myb][s2];
            float m = fmaxf(v1 ? -1e30f : u_l[myb][s1], v2 ? -1e30f : u_l[myb][s2]);
            for (int off = 32; off; off >>= 1) m = fmaxf(m, __shfl_xor(m, off, 64));
            float e1 = v1 ? 0.f : expf(u_l[myb][s1] - m);
            float e2 = v2 ? 0.f : expf(u_l[myb][s2] - m);
            float den = e1 + e2;
            for (int off = 32; off; off >>= 1) den += __shfl_xor(den, off, 64);
            uint32_t kk0, kk1;
            tf2x32(0u, 1u, 0u, (uint32_t)t, kk0, kk1);
            double z1 = v1 ? -1.0e300 : (double)u_l[myb][s1] + gumbel_jax(kk0, kk1, (uint32_t)(gb * 128 + s1));
            double z2 = v2 ? -1.0e300 : (double)u_l[myb][s2] + gumbel_jax(kk0, kk1, (uint32_t)(gb * 128 + s2));
            double bz; int bi;
            if (z2 > z1) { bz = z2; bi = s2; } else { bz = z1; bi = s1; }
            for (int off = 32; off; off >>= 1) {
                double oz = __shfl_xor(bz, off, 64);
                int oi = __shfl_xor(bi, off, 64);
                if (oz > bz || (oz == bz && oi < bi)) { bz = oz; bi = oi; }
            }
            if (lane == 0) {
                float pr = expf(u_l[myb][bi] - m) / den;
                out[t * NBATCH + gb] = pr;
                out[SLEN * NBATCH + t * NBATCH + gb] = (float)bi;
                vis[myb][bi] = 1;
                lastA[myb] = bi;
            }
        }
        __syncthreads();
    }
}

extern "C" void kernel_launch(void* const* d_in, const int* in_sizes, int n_in,
                              void* d_out, int out_size, void* d_ws, size_t ws_size,
                              hipStream_t stream) {
    (void)d_ws; (void)ws_size; (void)n_in; (void)in_sizes; (void)out_size;
    const float* problems = (const float*)d_in[0];
    const float* embed_W  = (const float*)d_in[1];
    const float* embed_b  = (const float*)d_in[2];
    const float* Wi_enc   = (const float*)d_in[3];
    const float* Wh_enc   = (const float*)d_in[4];
    const float* b_enc    = (const float*)d_in[5];
    const float* Wi_dec   = (const float*)d_in[6];
    const float* Wh_dec   = (const float*)d_in[7];
    const float* b_dec    = (const float*)d_in[8];
    const float* dec0     = (const float*)d_in[9];
    const float* Wq_g     = (const float*)d_in[10];
    const float* bq_g     = (const float*)d_in[11];
    const float* Wr_g     = (const float*)d_in[12];
    const float* br_g     = (const float*)d_in[13];
    const float* V_g      = (const float*)d_in[14];
    const float* Wq_p     = (const float*)d_in[15];
    const float* bq_p     = (const float*)d_in[16];
    const float* Wr_p     = (const float*)d_in[17];
    const float* br_p     = (const float*)d_in[18];
    const float* V_p      = (const float*)d_in[19];
    float* outp = (float*)d_out;

    hipLaunchKernelGGL(pre_k, dim3(512), dim3(256), 0, stream,
                       embed_W, embed_b, Wi_enc, Wh_enc, b_enc,
                       Wi_dec, Wh_dec, b_dec, dec0, Wq_g, Wr_g, Wq_p, Wr_p);
    hipLaunchKernelGGL(main_k, dim3(256), dim3(512), 0, stream,
                       problems, bq_g, br_g, V_g, bq_p, br_p, V_p, outp);
}